// Round 13
// baseline (339.209 us; speedup 1.0000x reference)
//
#include <hip/hip_runtime.h>
#include <hip/hip_bf16.h>
#include <math.h>

// ---------------------------------------------------------------------------
// MHLA: out, l_kv = MLA(x, cache, W_kv, W_q, W_lq, W_o)
//   l_kv_new = x @ W_kv ; lq = x @ (W_q @ W_lq) * 1/sqrt(512)  [folded+scaled]
//   l_kv = concat(cache, l_kv_new)
//   P = exp(lq @ l_kv^T)  (fp16, chunked; exp in the S-GEMM epilogue, which
//       also emits per-(row, col-block) sum-exp -> 1/l)
//   ctx = (P @ l_kv) * (1/l)   [256-tile split-K x8 -> fp16 partials -> reduce]
//   out = ctx @ W_o
// Softmax without max-subtraction (scores bounded; exp clamped at 60000).
// S/PV/out GEMMs on the 256x256 8-wave counted-vmcnt core (+setprio on MFMA
// clusters); fused/Wcomb GEMMs on the 128x128 reg-staged core.
// ---------------------------------------------------------------------------

typedef _Float16 f16x8 __attribute__((ext_vector_type(8)));
typedef _Float16 f16x4 __attribute__((ext_vector_type(4)));
typedef float    f32x4 __attribute__((ext_vector_type(4)));
typedef float    f32x8 __attribute__((ext_vector_type(8)));

// async 16B global->LDS (per-lane global addr; LDS dest = uniform base + lane*16)
__device__ __forceinline__ void gl_lds16(const void* g, void* l) {
  __builtin_amdgcn_global_load_lds(
      (const __attribute__((address_space(1))) void*)g,
      (__attribute__((address_space(3))) void*)l, 16, 0, 0);
}

// ---------------------------- elementwise converts -------------------------

__global__ __launch_bounds__(256) void k_cvt(const float* __restrict__ in,
                                             _Float16* __restrict__ out, int n4) {
  int i = blockIdx.x * blockDim.x + threadIdx.x;
  int st = gridDim.x * blockDim.x;
  for (; i < n4; i += st) {
    f32x4 v = reinterpret_cast<const f32x4*>(in)[i];
    reinterpret_cast<f16x4*>(out)[i] = __builtin_convertvector(v, f16x4);
  }
}

// cache (2,4096,512) -> l_kv f32 out rows [b*8192 + t] and fp16 copy
__global__ __launch_bounds__(256) void k_cache(const float* __restrict__ cache,
                                               float* __restrict__ lkv_f32,
                                               _Float16* __restrict__ lkv16, int n4) {
  int i = blockIdx.x * blockDim.x + threadIdx.x;
  int st = gridDim.x * blockDim.x;
  for (; i < n4; i += st) {
    f32x4 v = reinterpret_cast<const f32x4*>(cache)[i];
    int e = i << 2;
    int b = e >> 21;                 // 4096*512 = 2^21
    int dst = e + (b << 21);         // batch stride in l_kv is 2^22
    *reinterpret_cast<f32x4*>(lkv_f32 + dst) = v;
    *reinterpret_cast<f16x4*>(lkv16 + dst) = __builtin_convertvector(v, f16x4);
  }
}

// transpose+convert: in f32 (R x C) -> out fp16 (C x R)
__global__ __launch_bounds__(256) void k_tc(const float* __restrict__ in,
                                            _Float16* __restrict__ out, int R, int C) {
  __shared__ float t[32][33];
  const int c0 = blockIdx.x << 5, r0 = blockIdx.y << 5;
  const int tid = threadIdx.x;
  {
    int r = tid >> 3, c4 = (tid & 7) << 2;
    f32x4 v = *reinterpret_cast<const f32x4*>(&in[(long)(r0 + r) * C + c0 + c4]);
    t[r][c4] = v[0]; t[r][c4 + 1] = v[1]; t[r][c4 + 2] = v[2]; t[r][c4 + 3] = v[3];
  }
  __syncthreads();
  {
    int c = tid >> 3, r4 = (tid & 7) << 2;
    f16x4 o = {(_Float16)t[r4][c], (_Float16)t[r4 + 1][c],
               (_Float16)t[r4 + 2][c], (_Float16)t[r4 + 3][c]};
    *reinterpret_cast<f16x4*>(&out[(long)(c0 + c) * R + r0 + r4]) = o;
  }
}

// transpose fp16: in (R x C) -> out (C x R)
__global__ __launch_bounds__(256) void k_tb(const _Float16* __restrict__ in,
                                            _Float16* __restrict__ out, int R, int C) {
  __shared__ _Float16 t[32][36];
  const int c0 = blockIdx.x << 5, r0 = blockIdx.y << 5;
  const int tid = threadIdx.x;
  {
    int r = tid >> 3, c4 = (tid & 7) << 2;
    f16x4 v = *reinterpret_cast<const f16x4*>(&in[(long)(r0 + r) * C + c0 + c4]);
    t[r][c4] = v[0]; t[r][c4 + 1] = v[1]; t[r][c4 + 2] = v[2]; t[r][c4 + 3] = v[3];
  }
  __syncthreads();
  {
    int c = tid >> 3, r4 = (tid & 7) << 2;
    f16x4 o = {t[r4][c], t[r4 + 1][c], t[r4 + 2][c], t[r4 + 3][c]};
    *reinterpret_cast<f16x4*>(&out[(long)(c0 + c) * R + r0 + r4]) = o;
  }
}

// ------------------------- GEMM (128x128, reg-staged) ----------------------
// C[M,N] = A[M,K] @ B^T where A is [M][lda], B is [N][ldb] (K-contig rows).
// AF32/BF32: f32 operand converted during staging. SWZ: XCD-chunked remap.
// CMODE: 0 f32 C ; 1 fp16 C ; 3 fp16 scaled ; 4 split-K f32 partial ;
// 5 fused lq|lkv epilogue.
template <int CMODE, int AF32, int BF32, int SWZ>
__global__ __launch_bounds__(256) void k_gemm(const void* __restrict__ Av,
                                              const void* __restrict__ Bv,
                                              float* __restrict__ Cf,
                                              _Float16* __restrict__ Ch,
                                              _Float16* __restrict__ Ch2,
                                              int M, int N, int K, int lda, int ldb,
                                              float cscale) {
  const _Float16* A16 = (const _Float16*)Av;
  const float*    A32 = (const float*)Av;
  const _Float16* B16 = (const _Float16*)Bv;
  const float*    B32 = (const float*)Bv;
  if constexpr (CMODE == 4) {
    const long z = blockIdx.z;
    A16 += z * K; A32 += z * K;
    B16 += z * K; B32 += z * K;
    Cf += z * (long)M * N;
  }
  int bxr = blockIdx.x, byr = blockIdx.y;
  if constexpr (SWZ) {
    const int nbx = gridDim.x, nby = gridDim.y, nwg = nbx * nby;
    if ((nwg & 7) == 0) {
      const int orig = bxr * nby + byr;
      const int q = nwg >> 3;
      const int wg = (orig & 7) * q + (orig >> 3);
      bxr = wg / nby; byr = wg % nby;
    }
  }
  __shared__ alignas(16) _Float16 As[128 * 64];
  __shared__ alignas(16) _Float16 Bs[128 * 64];
  const int tid = threadIdx.x;
  const int lane = tid & 63;
  const int w = tid >> 6;
  const int wr = ((w >> 1) & 1) << 6, wc = (w & 1) << 6;
  const int bm = bxr << 7, bn = byr << 7;
  const int g = lane >> 4, ln15 = lane & 15;

  f32x4 acc[4][4] = {};

  const int srowl = lane >> 3;
  const int skcol = (lane & 7) << 3;
  const int wofs = (srowl << 6) + (((lane & 7) ^ srowl) << 3);

  f16x8 ra[4], rb[4];
  auto loadregs = [&](int k0) {
#pragma unroll
    for (int i = 0; i < 4; ++i) {
      int ch = (w << 2) + i;
      int row = (ch << 3) + srowl;
      if constexpr (AF32) {
        f32x8 v = *reinterpret_cast<const f32x8*>(&A32[(long)(bm + row) * lda + k0 + skcol]);
        ra[i] = __builtin_convertvector(v, f16x8);
      } else {
        ra[i] = *reinterpret_cast<const f16x8*>(&A16[(long)(bm + row) * lda + k0 + skcol]);
      }
      if constexpr (BF32) {
        f32x8 v = *reinterpret_cast<const f32x8*>(&B32[(long)(bn + row) * ldb + k0 + skcol]);
        rb[i] = __builtin_convertvector(v, f16x8);
      } else {
        rb[i] = *reinterpret_cast<const f16x8*>(&B16[(long)(bn + row) * ldb + k0 + skcol]);
      }
    }
  };
  loadregs(0);
  const int nk = K >> 6;
  for (int kt = 0; kt < nk; ++kt) {
    __syncthreads();
#pragma unroll
    for (int i = 0; i < 4; ++i) {
      int ch = (w << 2) + i;
      *reinterpret_cast<f16x8*>(&As[(ch << 9) + wofs]) = ra[i];
      *reinterpret_cast<f16x8*>(&Bs[(ch << 9) + wofs]) = rb[i];
    }
    __syncthreads();
    if (kt + 1 < nk) loadregs((kt + 1) << 6);
#pragma unroll
    for (int ks = 0; ks < 2; ++ks) {
      f16x8 af[4], bf[4];
#pragma unroll
      for (int i = 0; i < 4; ++i) {
        const int arow = wr + (i << 4) + ln15;
        const int brow = wc + (i << 4) + ln15;
        const int inner = (((ks << 5) + (g << 3)) ^ ((ln15 & 7) << 3));
        af[i] = *reinterpret_cast<const f16x8*>(&As[arow * 64 + inner]);
        bf[i] = *reinterpret_cast<const f16x8*>(&Bs[brow * 64 + inner]);
      }
#pragma unroll
      for (int i = 0; i < 4; ++i)
#pragma unroll
        for (int j = 0; j < 4; ++j)
          acc[i][j] = __builtin_amdgcn_mfma_f32_16x16x32_f16(af[i], bf[j], acc[i][j], 0, 0, 0);
    }
  }
#pragma unroll
  for (int i = 0; i < 4; ++i) {
    const int row = bm + wr + (i << 4) + (g << 2);
#pragma unroll
    for (int j = 0; j < 4; ++j) {
      const int col = bn + wc + (j << 4) + ln15;
#pragma unroll
      for (int r = 0; r < 4; ++r) {
        float v = acc[i][j][r];
        long orow = row + r;
        if constexpr (CMODE == 1) {
          Ch[orow * N + col] = (_Float16)v;
        } else if constexpr (CMODE == 3) {
          Ch[orow * N + col] = (_Float16)(v * cscale);
        } else if constexpr (CMODE == 5) {
          if (col < 512) {
            Ch[orow * 512 + col] = (_Float16)v;               // lq16
          } else {
            long m2 = ((orow >> 12) << 13) + 4096 + (orow & 4095);
            Cf[m2 * 512 + (col - 512)] = v;                   // l_kv f32
            Ch2[m2 * 512 + (col - 512)] = (_Float16)v;        // l_kv fp16
          }
        } else {  // 0, 4
          Cf[orow * N + col] = v;
        }
      }
    }
  }
}

// ---------------- GEMM (256x256, 8 waves, counted-vmcnt pipeline) ----------
// 2-deep global_load_lds prefetch; raw s_barrier + s_waitcnt vmcnt(8);
// setprio(1) around MFMA clusters (waves desync between barriers -> role
// split for the CU scheduler). M-major XCD-chunked block remap.
// CMODE: 0 = f32 C, 1 = fp16 C.
// STATS=1: store (fp16)min(exp(acc),60000) + per-(row, col-block) sum-exp.
// SPLITK=1: blockIdx.z = K-slice (K is per-slice depth); fp16 partials in Ch.
template <int CMODE, int STATS, int SPLITK>
__global__ __launch_bounds__(512, 2) void k_gemm256(const _Float16* __restrict__ A,
                                                    const _Float16* __restrict__ B,
                                                    float* __restrict__ Cf,
                                                    _Float16* __restrict__ Ch,
                                                    float* __restrict__ Lp,
                                                    int M, int N, int K,
                                                    int lda, int ldb) {
  extern __shared__ _Float16 sm[];
  _Float16* As = sm;             // [2][256*64]
  _Float16* Bs = sm + 32768;     // [2][256*64]
  if constexpr (SPLITK) {
    const long z = blockIdx.z;
    A += z * (long)K;            // K-slice offset within row (lda/ldb full)
    B += z * (long)K;
    Ch += z * (long)M * N;
  }
  int bxr = blockIdx.x, byr = blockIdx.y;
  {
    const int nbx = gridDim.x, nby = gridDim.y, nwg = nbx * nby;
    if ((nwg & 7) == 0) {
      const int orig = bxr * nby + byr;      // M-major linearization
      const int q = nwg >> 3;
      const int wg = (orig & 7) * q + (orig >> 3);  // XCD-chunked (bijective)
      bxr = wg / nby; byr = wg % nby;
    }
  }
  const int tid = threadIdx.x;
  const int lane = tid & 63;
  const int w = tid >> 6;             // 0..7
  const int wm = w >> 2, wn = w & 3;  // 2 x 4 wave grid; wave out = 128x64
  const int bm = bxr << 8, bn = byr << 8;
  const int g = lane >> 4, ln15 = lane & 15;

  f32x4 acc[8][4] = {};

  const int lrow8 = lane >> 3;
  const int lswz  = ((lane & 7) ^ lrow8) << 3;
  const _Float16* Ap[4];
  const _Float16* Bp[4];
  int loff[4];
#pragma unroll
  for (int i = 0; i < 4; ++i) {
    const int row = (i << 6) + (w << 3) + lrow8;
    Ap[i] = &A[(long)(bm + row) * lda + lswz];
    Bp[i] = &B[(long)(bn + row) * ldb + lswz];
    loff[i] = ((i << 6) + (w << 3)) << 6;   // (row base) * 64 elems
  }

  auto stage = [&](int buf, int kt) {
    const int k0 = kt << 6;
    const int bo = buf << 14;
#pragma unroll
    for (int i = 0; i < 4; ++i) {
      gl_lds16(Ap[i] + k0, &As[bo + loff[i]]);
      gl_lds16(Bp[i] + k0, &Bs[bo + loff[i]]);
    }
  };

  const int nk = K >> 6;
  stage(0, 0);
  if (nk > 1) stage(1, 1);

  for (int kt = 0; kt < nk; ++kt) {
    if (kt + 1 < nk) asm volatile("s_waitcnt vmcnt(8)" ::: "memory");
    else             asm volatile("s_waitcnt vmcnt(0)" ::: "memory");
    __builtin_amdgcn_sched_barrier(0);
    __builtin_amdgcn_s_barrier();          // all waves' tile-kt DMA visible
    const int bo = (kt & 1) << 14;
#pragma unroll
    for (int ks = 0; ks < 2; ++ks) {
      f16x8 af[8], bf[4];
      const int innersw = ((ks << 5) + (g << 3)) ^ ((ln15 & 7) << 3);
#pragma unroll
      for (int i = 0; i < 8; ++i) {
        const int arow = (wm << 7) + (i << 4) + ln15;
        af[i] = *reinterpret_cast<const f16x8*>(&As[bo + arow * 64 + innersw]);
      }
#pragma unroll
      for (int j = 0; j < 4; ++j) {
        const int brow = (wn << 6) + (j << 4) + ln15;
        bf[j] = *reinterpret_cast<const f16x8*>(&Bs[bo + brow * 64 + innersw]);
      }
      __builtin_amdgcn_s_setprio(1);
#pragma unroll
      for (int i = 0; i < 8; ++i)
#pragma unroll
        for (int j = 0; j < 4; ++j)
          acc[i][j] = __builtin_amdgcn_mfma_f32_16x16x32_f16(af[i], bf[j], acc[i][j], 0, 0, 0);
      __builtin_amdgcn_s_setprio(0);
    }
    asm volatile("s_waitcnt lgkmcnt(0)" ::: "memory");
    __builtin_amdgcn_sched_barrier(0);
    __builtin_amdgcn_s_barrier();          // WAR: no wave still reading buf
    if (kt + 2 < nk) stage(kt & 1, kt + 2);
  }

  // epilogue: D frag row = g*4 + r, col = ln15
  if constexpr (STATS) {
    // store P = exp(s) (fp16) and accumulate per-row sum-exp (f32).
    float* Lsh = (float*)sm;   // [256][4] — staging LDS is dead here
    float part[8][4];
#pragma unroll
    for (int i = 0; i < 8; ++i) {
      const int row = bm + (wm << 7) + (i << 4) + (g << 2);
#pragma unroll
      for (int r = 0; r < 4; ++r) {
        float s = 0.f;
#pragma unroll
        for (int j = 0; j < 4; ++j) {
          const int col = bn + (wn << 6) + (j << 4) + ln15;
          float e = fminf(__expf(acc[i][j][r]), 60000.f);
          Ch[(long)(row + r) * N + col] = (_Float16)e;
          s += e;
        }
        // reduce across the 16 lanes sharing g (xor 1,2,4,8 stay in-group)
#pragma unroll
        for (int off = 1; off < 16; off <<= 1) s += __shfl_xor(s, off);
        part[i][r] = s;
      }
    }
    if (ln15 == 0) {
#pragma unroll
      for (int i = 0; i < 8; ++i)
#pragma unroll
        for (int r = 0; r < 4; ++r) {
          const int lrow = (wm << 7) + (i << 4) + (g << 2) + r;
          Lsh[(lrow << 2) + wn] = part[i][r];
        }
    }
    __syncthreads();
    if (tid < 256) {
      float L = Lsh[(tid << 2)] + Lsh[(tid << 2) + 1] +
                Lsh[(tid << 2) + 2] + Lsh[(tid << 2) + 3];
      Lp[(long)(bm + tid) * gridDim.y + byr] = L;
    }
  } else {
#pragma unroll
    for (int i = 0; i < 8; ++i) {
      const int row = bm + (wm << 7) + (i << 4) + (g << 2);
#pragma unroll
      for (int j = 0; j < 4; ++j) {
        const int col = bn + (wn << 6) + (j << 4) + ln15;
#pragma unroll
        for (int r = 0; r < 4; ++r) {
          if constexpr (CMODE == 1)
            Ch[(long)(row + r) * N + col] = (_Float16)acc[i][j][r];
          else
            Cf[(long)(row + r) * N + col] = acc[i][j][r];
        }
      }
    }
  }
}

// ----------------- combine per-block sum-exp -> 1/l per row -----------------
__global__ __launch_bounds__(256) void k_linv(const float* __restrict__ Lp,
                                              float* __restrict__ Linv, int nb) {
  const int r = (blockIdx.x << 8) + threadIdx.x;
  float s = 0.f;
  for (int i = 0; i < nb; ++i) s += Lp[(long)r * nb + i];
  Linv[r] = 1.f / s;
}

// --------------------- split-K reduce: sum 4 f32 slices -> fp16 -------------
__global__ __launch_bounds__(256) void k_red4(const float* __restrict__ p,
                                              _Float16* __restrict__ o,
                                              int n4, float scale) {
  const f32x4* pv = reinterpret_cast<const f32x4*>(p);
  int i = blockIdx.x * blockDim.x + threadIdx.x;
  int st = gridDim.x * blockDim.x;
  for (; i < n4; i += st) {
    f32x4 a = pv[i] + pv[i + n4] + pv[i + 2 * n4] + pv[i + 3 * n4];
    a *= scale;
    reinterpret_cast<f16x4*>(o)[i] = __builtin_convertvector(a, f16x4);
  }
}

// ------ split-K reduce of 8 fp16 slices with per-row 1/l scale (PV->ctx) ----
__global__ __launch_bounds__(256) void k_red8row(const _Float16* __restrict__ p,
                                                 const float* __restrict__ Linv,
                                                 _Float16* __restrict__ o, int n4) {
  const f16x4* pv = reinterpret_cast<const f16x4*>(p);
  int i = blockIdx.x * blockDim.x + threadIdx.x;
  int st = gridDim.x * blockDim.x;
  for (; i < n4; i += st) {
    f32x4 a = __builtin_convertvector(pv[i], f32x4);
#pragma unroll
    for (int s = 1; s < 8; ++s)
      a += __builtin_convertvector(pv[i + (long)s * n4], f32x4);
    a *= Linv[i >> 7];                      // 128 f16x4 groups per 512-col row
    reinterpret_cast<f16x4*>(o)[i] = __builtin_convertvector(a, f16x4);
  }
}

// ------------------------------- launcher ----------------------------------

extern "C" void kernel_launch(void* const* d_in, const int* in_sizes, int n_in,
                              void* d_out, int out_size, void* d_ws, size_t ws_size,
                              hipStream_t stream) {
  const float* x     = (const float*)d_in[0];
  const float* cache = (const float*)d_in[1];
  const float* W_kv  = (const float*)d_in[2];
  const float* W_q   = (const float*)d_in[3];
  const float* W_lq  = (const float*)d_in[4];
  const float* W_o   = (const float*)d_in[5];

  float* out     = (float*)d_out;                 // (8192, 2048) f32
  float* lkv_out = out + (size_t)8192 * 2048;     // (2, 8192, 512) f32

  // scratch overlay in d_out's "out" region (dead before final GEMM writes it)
  _Float16* base16 = (_Float16*)d_out;
  _Float16* x16    = base16;                      // [0, 16.78M) live->fused GEMM
  _Float16* lq16   = base16 + 16777216;           // live -> S-GEMM
  _Float16* WlqT   = base16 + 25165824;           // dead after Wcomb GEMM
  _Float16* WcombT = base16 + 26214400;           // dead after fused GEMM
  _Float16* WkvT   = base16 + 27262976;           // adjacent to WcombT (B concat)
  _Float16* lkvT16 = base16 + 20971520;           // spans ..29,360,128
  _Float16* PVp16  = base16;                      // PV fp16 partials overlay x16
                                                  // (8 * CR * 512 * 2B <= 33.5MB)
  float*    Lp     = (float*)(base16 + 29360128); // CR*32 f32 (<=512KB)
  float*    Linv   = Lp + 131072;                 // CR f32

  // ws: lkv16 16.8MB | ctx 8.4MB | WoT 2MB | S chunk
  _Float16* lkv16 = (_Float16*)d_ws;              // 8,388,608 elems
  _Float16* ctx   = lkv16 + 8388608;              // 4,194,304
  _Float16* WoT   = ctx + 4194304;                // 1,048,576
  _Float16* Sbuf  = WoT + 1048576;                // CR*8192 elems
  float*    Wcp   = (float*)Sbuf;                 // Wcomb split-K f32 partials

  // S chunk rows: pick largest fitting ws_size (base usage = 27,262,976 B)
  const size_t sbase = 27262976;
  int CR = 1024;
  if (ws_size >= sbase + (size_t)4096 * 8192 * 2) CR = 4096;
  else if (ws_size >= sbase + (size_t)2048 * 8192 * 2) CR = 2048;

  const float iscale = 0.044194173824159216f;  // 1/sqrt(512)

  hipFuncSetAttribute((const void*)k_gemm256<1, 1, 0>,
                      hipFuncAttributeMaxDynamicSharedMemorySize, 131072);
  hipFuncSetAttribute((const void*)k_gemm256<0, 0, 0>,
                      hipFuncAttributeMaxDynamicSharedMemorySize, 131072);
  hipFuncSetAttribute((const void*)k_gemm256<1, 0, 1>,
                      hipFuncAttributeMaxDynamicSharedMemorySize, 131072);

  // converts / transposes (W_q consumed f32-direct; x pre-converted: the
  // fused GEMM re-reads A 8x, so one-pass fp16 conversion wins)
  k_cvt<<<1024, 256, 0, stream>>>(x, x16, 16777216 / 4);
  k_cache<<<1024, 256, 0, stream>>>(cache, lkv_out, lkv16, 4194304 / 4);
  k_tc<<<dim3(16, 64), 256, 0, stream>>>(W_kv, WkvT, 2048, 512);
  k_tc<<<dim3(16, 64), 256, 0, stream>>>(W_lq, WlqT, 2048, 512);
  k_tc<<<dim3(64, 16), 256, 0, stream>>>(W_o, WoT, 512, 2048);

  // W_comb^T[l][d] = sum_e WlqT[l][e]*W_q[d][e] : split-K x4 (B read f32)
  k_gemm<4, 0, 1, 0><<<dim3(4, 16, 4), 256, 0, stream>>>(
      WlqT, W_q, Wcp, nullptr, nullptr, 512, 2048, 512, 2048, 2048, 1.f);
  k_red4<<<1024, 256, 0, stream>>>(Wcp, WcombT, (512 * 2048) / 4, iscale);
  // fused: [lq | l_kv_new] = x16 @ [WcombT ; WkvT]^T  (N=1024, XCD swizzle)
  k_gemm<5, 0, 0, 1><<<dim3(64, 8), 256, 0, stream>>>(
      x16, WcombT, lkv_out, lq16, lkv16, 8192, 1024, 2048, 2048, 2048, 1.f);
  // l_kv^T (512 x 16384) into d_out spare
  k_tb<<<dim3(16, 512), 256, 0, stream>>>(lkv16, lkvT16, 16384, 512);

  // attention per CR-row chunk: P=exp(S) (+sum-exp), 1/l, PV, scaled reduce
  for (long r0 = 0; r0 < 8192; r0 += CR) {
    const long b = r0 >> 12;
    // P = exp(lq_chunk @ l_kv_b^T)  (fp16) + per-(row, col-block) sum-exp
    k_gemm256<1, 1, 0><<<dim3(CR >> 8, 32), 512, 131072, stream>>>(
        lq16 + r0 * 512, lkv16 + b * 8192 * 512, nullptr, Sbuf, Lp,
        CR, 8192, 512, 512, 512);
    k_linv<<<CR >> 8, 256, 0, stream>>>(Lp, Linv, 32);
    // ctx_chunk = P @ V : 256-tile split-K x8 (Ks=1024) -> fp16 partials
    k_gemm256<1, 0, 1><<<dim3(CR >> 8, 2, 8), 512, 131072, stream>>>(
        Sbuf, lkvT16 + b * 8192, nullptr, PVp16, nullptr,
        CR, 512, 1024, 8192, 16384);
    // reduce 8 slices + per-row 1/l
    k_red8row<<<2048, 256, 0, stream>>>(PVp16, Linv, ctx + r0 * 512, (CR * 512) / 4);
  }

  // out = ctx @ W_o — 256-tile counted-vmcnt core
  k_gemm256<0, 0, 0><<<dim3(32, 8), 512, 131072, stream>>>(ctx, WoT, out, nullptr,
                                                           nullptr,
                                                           8192, 2048, 512, 512, 512);
}

// Round 14
// 332.580 us; speedup vs baseline: 1.0199x; 1.0199x over previous
//
#include <hip/hip_runtime.h>
#include <hip/hip_bf16.h>
#include <math.h>

// ---------------------------------------------------------------------------
// MHLA: out, l_kv = MLA(x, cache, W_kv, W_q, W_lq, W_o)
//   l_kv_new = x @ W_kv ; lq = x @ (W_q @ W_lq) * 1/sqrt(512)  [folded+scaled]
//   l_kv = concat(cache, l_kv_new)
//   P = exp(lq @ l_kv^T)  (fp16, chunked; exp + row sum-exp in S-GEMM epilogue)
//   ctx = (P @ l_kv) * (1/l)   [256-tile split-K x8 -> fp16 partials -> reduce]
//   out = ctx @ W_o
// k_gemm256 now runs a 4-phase/K-tile counted-vmcnt pipeline (T3+T4):
//   per phase: ds_read subtile -> stage 1 half-tile -> bar -> lgkm(0) ->
//   16 MFMA (setprio) -> [vmcnt(4) once per K-tile] -> bar.
// Wait ledger (per wave, 2 loads per half-tile stage):
//   prologue: B(0),A(0),B(1) staged; vmcnt(4) leaves B(1) in flight.
//   kt stages A(kt+1) @P0,P1 and B(kt+2) @P2,P3; vmcnt(4) at P3 end ensures
//   A(kt+1),B(kt+1) resident (newest 4 = B(kt+2)); tail degrades to vmcnt(0).
//   WAR: A-slot last read kt-1 P3 < trailing bar < kt P0 stage; B-slot read
//   only in P0 (regs) < P0 trailing bar < P2 stage.
// ---------------------------------------------------------------------------

typedef _Float16 f16x8 __attribute__((ext_vector_type(8)));
typedef _Float16 f16x4 __attribute__((ext_vector_type(4)));
typedef float    f32x4 __attribute__((ext_vector_type(4)));
typedef float    f32x8 __attribute__((ext_vector_type(8)));

// async 16B global->LDS (per-lane global addr; LDS dest = uniform base + lane*16)
__device__ __forceinline__ void gl_lds16(const void* g, void* l) {
  __builtin_amdgcn_global_load_lds(
      (const __attribute__((address_space(1))) void*)g,
      (__attribute__((address_space(3))) void*)l, 16, 0, 0);
}

// ---------------------------- elementwise converts -------------------------

__global__ __launch_bounds__(256) void k_cvt(const float* __restrict__ in,
                                             _Float16* __restrict__ out, int n4) {
  int i = blockIdx.x * blockDim.x + threadIdx.x;
  int st = gridDim.x * blockDim.x;
  for (; i < n4; i += st) {
    f32x4 v = reinterpret_cast<const f32x4*>(in)[i];
    reinterpret_cast<f16x4*>(out)[i] = __builtin_convertvector(v, f16x4);
  }
}

// cache (2,4096,512) -> l_kv f32 out rows [b*8192 + t] and fp16 copy
__global__ __launch_bounds__(256) void k_cache(const float* __restrict__ cache,
                                               float* __restrict__ lkv_f32,
                                               _Float16* __restrict__ lkv16, int n4) {
  int i = blockIdx.x * blockDim.x + threadIdx.x;
  int st = gridDim.x * blockDim.x;
  for (; i < n4; i += st) {
    f32x4 v = reinterpret_cast<const f32x4*>(cache)[i];
    int e = i << 2;
    int b = e >> 21;                 // 4096*512 = 2^21
    int dst = e + (b << 21);         // batch stride in l_kv is 2^22
    *reinterpret_cast<f32x4*>(lkv_f32 + dst) = v;
    *reinterpret_cast<f16x4*>(lkv16 + dst) = __builtin_convertvector(v, f16x4);
  }
}

// transpose+convert: in f32 (R x C) -> out fp16 (C x R)
__global__ __launch_bounds__(256) void k_tc(const float* __restrict__ in,
                                            _Float16* __restrict__ out, int R, int C) {
  __shared__ float t[32][33];
  const int c0 = blockIdx.x << 5, r0 = blockIdx.y << 5;
  const int tid = threadIdx.x;
  {
    int r = tid >> 3, c4 = (tid & 7) << 2;
    f32x4 v = *reinterpret_cast<const f32x4*>(&in[(long)(r0 + r) * C + c0 + c4]);
    t[r][c4] = v[0]; t[r][c4 + 1] = v[1]; t[r][c4 + 2] = v[2]; t[r][c4 + 3] = v[3];
  }
  __syncthreads();
  {
    int c = tid >> 3, r4 = (tid & 7) << 2;
    f16x4 o = {(_Float16)t[r4][c], (_Float16)t[r4 + 1][c],
               (_Float16)t[r4 + 2][c], (_Float16)t[r4 + 3][c]};
    *reinterpret_cast<f16x4*>(&out[(long)(c0 + c) * R + r0 + r4]) = o;
  }
}

// transpose fp16: in (R x C) -> out (C x R)
__global__ __launch_bounds__(256) void k_tb(const _Float16* __restrict__ in,
                                            _Float16* __restrict__ out, int R, int C) {
  __shared__ _Float16 t[32][36];
  const int c0 = blockIdx.x << 5, r0 = blockIdx.y << 5;
  const int tid = threadIdx.x;
  {
    int r = tid >> 3, c4 = (tid & 7) << 2;
    f16x4 v = *reinterpret_cast<const f16x4*>(&in[(long)(r0 + r) * C + c0 + c4]);
    t[r][c4] = v[0]; t[r][c4 + 1] = v[1]; t[r][c4 + 2] = v[2]; t[r][c4 + 3] = v[3];
  }
  __syncthreads();
  {
    int c = tid >> 3, r4 = (tid & 7) << 2;
    f16x4 o = {t[r4][c], t[r4 + 1][c], t[r4 + 2][c], t[r4 + 3][c]};
    *reinterpret_cast<f16x4*>(&out[(long)(c0 + c) * R + r0 + r4]) = o;
  }
}

// ------------------------- GEMM (128x128, reg-staged) ----------------------
// C[M,N] = A[M,K] @ B^T where A is [M][lda], B is [N][ldb] (K-contig rows).
// AF32/BF32: f32 operand converted during staging. SWZ: XCD-chunked remap.
// CMODE: 0 f32 C ; 1 fp16 C ; 3 fp16 scaled ; 4 split-K f32 partial ;
// 5 fused lq|lkv epilogue.
template <int CMODE, int AF32, int BF32, int SWZ>
__global__ __launch_bounds__(256) void k_gemm(const void* __restrict__ Av,
                                              const void* __restrict__ Bv,
                                              float* __restrict__ Cf,
                                              _Float16* __restrict__ Ch,
                                              _Float16* __restrict__ Ch2,
                                              int M, int N, int K, int lda, int ldb,
                                              float cscale) {
  const _Float16* A16 = (const _Float16*)Av;
  const float*    A32 = (const float*)Av;
  const _Float16* B16 = (const _Float16*)Bv;
  const float*    B32 = (const float*)Bv;
  if constexpr (CMODE == 4) {
    const long z = blockIdx.z;
    A16 += z * K; A32 += z * K;
    B16 += z * K; B32 += z * K;
    Cf += z * (long)M * N;
  }
  int bxr = blockIdx.x, byr = blockIdx.y;
  if constexpr (SWZ) {
    const int nbx = gridDim.x, nby = gridDim.y, nwg = nbx * nby;
    if ((nwg & 7) == 0) {
      const int orig = bxr * nby + byr;
      const int q = nwg >> 3;
      const int wg = (orig & 7) * q + (orig >> 3);
      bxr = wg / nby; byr = wg % nby;
    }
  }
  __shared__ alignas(16) _Float16 As[128 * 64];
  __shared__ alignas(16) _Float16 Bs[128 * 64];
  const int tid = threadIdx.x;
  const int lane = tid & 63;
  const int w = tid >> 6;
  const int wr = ((w >> 1) & 1) << 6, wc = (w & 1) << 6;
  const int bm = bxr << 7, bn = byr << 7;
  const int g = lane >> 4, ln15 = lane & 15;

  f32x4 acc[4][4] = {};

  const int srowl = lane >> 3;
  const int skcol = (lane & 7) << 3;
  const int wofs = (srowl << 6) + (((lane & 7) ^ srowl) << 3);

  f16x8 ra[4], rb[4];
  auto loadregs = [&](int k0) {
#pragma unroll
    for (int i = 0; i < 4; ++i) {
      int ch = (w << 2) + i;
      int row = (ch << 3) + srowl;
      if constexpr (AF32) {
        f32x8 v = *reinterpret_cast<const f32x8*>(&A32[(long)(bm + row) * lda + k0 + skcol]);
        ra[i] = __builtin_convertvector(v, f16x8);
      } else {
        ra[i] = *reinterpret_cast<const f16x8*>(&A16[(long)(bm + row) * lda + k0 + skcol]);
      }
      if constexpr (BF32) {
        f32x8 v = *reinterpret_cast<const f32x8*>(&B32[(long)(bn + row) * ldb + k0 + skcol]);
        rb[i] = __builtin_convertvector(v, f16x8);
      } else {
        rb[i] = *reinterpret_cast<const f16x8*>(&B16[(long)(bn + row) * ldb + k0 + skcol]);
      }
    }
  };
  loadregs(0);
  const int nk = K >> 6;
  for (int kt = 0; kt < nk; ++kt) {
    __syncthreads();
#pragma unroll
    for (int i = 0; i < 4; ++i) {
      int ch = (w << 2) + i;
      *reinterpret_cast<f16x8*>(&As[(ch << 9) + wofs]) = ra[i];
      *reinterpret_cast<f16x8*>(&Bs[(ch << 9) + wofs]) = rb[i];
    }
    __syncthreads();
    if (kt + 1 < nk) loadregs((kt + 1) << 6);
#pragma unroll
    for (int ks = 0; ks < 2; ++ks) {
      f16x8 af[4], bf[4];
#pragma unroll
      for (int i = 0; i < 4; ++i) {
        const int arow = wr + (i << 4) + ln15;
        const int brow = wc + (i << 4) + ln15;
        const int inner = (((ks << 5) + (g << 3)) ^ ((ln15 & 7) << 3));
        af[i] = *reinterpret_cast<const f16x8*>(&As[arow * 64 + inner]);
        bf[i] = *reinterpret_cast<const f16x8*>(&Bs[brow * 64 + inner]);
      }
#pragma unroll
      for (int i = 0; i < 4; ++i)
#pragma unroll
        for (int j = 0; j < 4; ++j)
          acc[i][j] = __builtin_amdgcn_mfma_f32_16x16x32_f16(af[i], bf[j], acc[i][j], 0, 0, 0);
    }
  }
#pragma unroll
  for (int i = 0; i < 4; ++i) {
    const int row = bm + wr + (i << 4) + (g << 2);
#pragma unroll
    for (int j = 0; j < 4; ++j) {
      const int col = bn + wc + (j << 4) + ln15;
#pragma unroll
      for (int r = 0; r < 4; ++r) {
        float v = acc[i][j][r];
        long orow = row + r;
        if constexpr (CMODE == 1) {
          Ch[orow * N + col] = (_Float16)v;
        } else if constexpr (CMODE == 3) {
          Ch[orow * N + col] = (_Float16)(v * cscale);
        } else if constexpr (CMODE == 5) {
          if (col < 512) {
            Ch[orow * 512 + col] = (_Float16)v;               // lq16
          } else {
            long m2 = ((orow >> 12) << 13) + 4096 + (orow & 4095);
            Cf[m2 * 512 + (col - 512)] = v;                   // l_kv f32
            Ch2[m2 * 512 + (col - 512)] = (_Float16)v;        // l_kv fp16
          }
        } else {  // 0, 4
          Cf[orow * N + col] = v;
        }
      }
    }
  }
}

// ------- GEMM (256x256, 8 waves, 4-phase/K-tile counted-vmcnt pipeline) ----
// LDS per operand: 4 half-slots (2 bufs x 2 row-halves), 16KB each.
// Wave (wm,wn) consumes A-half wm (slot buf*2+wm) and B-half wn>>1.
// bf register-cached per K-tile (read @P0); af reloaded per phase.
// CMODE: 0 = f32 C, 1 = fp16 C. STATS=1: store exp(acc) + row sum-exp.
// SPLITK=1: blockIdx.z = K-slice; fp16 partials in Ch.
template <int CMODE, int STATS, int SPLITK>
__global__ __launch_bounds__(512, 2) void k_gemm256(const _Float16* __restrict__ A,
                                                    const _Float16* __restrict__ B,
                                                    float* __restrict__ Cf,
                                                    _Float16* __restrict__ Ch,
                                                    float* __restrict__ Lp,
                                                    int M, int N, int K,
                                                    int lda, int ldb) {
  extern __shared__ _Float16 sm[];
  _Float16* As = sm;             // 4 slots x 8192 elems (buf*2+half)
  _Float16* Bs = sm + 32768;
  if constexpr (SPLITK) {
    const long z = blockIdx.z;
    A += z * (long)K;
    B += z * (long)K;
    Ch += z * (long)M * N;
  }
  int bxr = blockIdx.x, byr = blockIdx.y;
  {
    const int nbx = gridDim.x, nby = gridDim.y, nwg = nbx * nby;
    if ((nwg & 7) == 0) {
      const int orig = bxr * nby + byr;      // M-major linearization
      const int q = nwg >> 3;
      const int wg = (orig & 7) * q + (orig >> 3);  // XCD-chunked (bijective)
      bxr = wg / nby; byr = wg % nby;
    }
  }
  const int tid = threadIdx.x;
  const int lane = tid & 63;
  const int w = tid >> 6;             // 0..7
  const int wm = w >> 2, wn = w & 3;  // 2 x 4 wave grid; wave out = 128x64
  const int bm = bxr << 8, bn = byr << 8;
  const int g = lane >> 4, ln15 = lane & 15;

  f32x4 acc[8][4] = {};

  const int lrow8 = lane >> 3;
  const int lswz  = ((lane & 7) ^ lrow8) << 3;   // pre-swizzled col (elems)
  const int nk = K >> 6;

  // stage one half-tile (128 rows x 64 cols) of operand for K-tile kt: 2 loads
  auto stageA = [&](int half, int kt) {
    const int slot = ((kt & 1) << 1) + half;
    const long k0 = (long)kt << 6;
#pragma unroll
    for (int l = 0; l < 2; ++l) {
      const int row = (half << 7) + (l << 6) + (w << 3) + lrow8;
      gl_lds16(&A[(long)(bm + row) * lda + k0 + lswz],
               &As[slot * 8192 + (((l << 6) + (w << 3)) << 6)]);
    }
  };
  auto stageB = [&](int half, int kt) {
    const int slot = ((kt & 1) << 1) + half;
    const long k0 = (long)kt << 6;
#pragma unroll
    for (int l = 0; l < 2; ++l) {
      const int row = (half << 7) + (l << 6) + (w << 3) + lrow8;
      gl_lds16(&B[(long)(bn + row) * ldb + k0 + lswz],
               &Bs[slot * 8192 + (((l << 6) + (w << 3)) << 6)]);
    }
  };

  // prologue: B(0), A(0), B(1); wait leaves only B(1) (4 loads) in flight
  stageB(0, 0); stageB(1, 0);
  stageA(0, 0); stageA(1, 0);
  if (nk > 1) { stageB(0, 1); stageB(1, 1); }
  if (nk > 1) asm volatile("s_waitcnt vmcnt(4)" ::: "memory");
  else        asm volatile("s_waitcnt vmcnt(0)" ::: "memory");
  __builtin_amdgcn_sched_barrier(0);
  __builtin_amdgcn_s_barrier();

  f16x8 bf[4][2];
  for (int kt = 0; kt < nk; ++kt) {
    const int aslot = ((kt & 1) << 1) + wm;
    const int bslot = ((kt & 1) << 1) + (wn >> 1);
    const int brow0 = (wn & 1) << 6;
#pragma unroll
    for (int p = 0; p < 4; ++p) {
      // --- ds_read register subtile
      if (p == 0) {
#pragma unroll
        for (int j = 0; j < 4; ++j)
#pragma unroll
          for (int ks = 0; ks < 2; ++ks) {
            const int inner = ((ks << 5) + (g << 3)) ^ ((ln15 & 7) << 3);
            bf[j][ks] = *reinterpret_cast<const f16x8*>(
                &Bs[bslot * 8192 + (brow0 + (j << 4) + ln15) * 64 + inner]);
          }
      }
      f16x8 af[2][2];
#pragma unroll
      for (int i = 0; i < 2; ++i)
#pragma unroll
        for (int ks = 0; ks < 2; ++ks) {
          const int mf = (p << 1) + i;
          const int inner = ((ks << 5) + (g << 3)) ^ ((ln15 & 7) << 3);
          af[i][ks] = *reinterpret_cast<const f16x8*>(
              &As[aslot * 8192 + ((mf << 4) + ln15) * 64 + inner]);
        }
      // --- stage 1 half-tile (pacing: A(kt+1) @P0,P1 ; B(kt+2) @P2,P3)
      if (p == 0 && kt + 1 < nk) stageA(0, kt + 1);
      if (p == 1 && kt + 1 < nk) stageA(1, kt + 1);
      if (p == 2 && kt + 2 < nk) stageB(0, kt + 2);
      if (p == 3 && kt + 2 < nk) stageB(1, kt + 2);
      __builtin_amdgcn_s_barrier();                        // mid
      asm volatile("s_waitcnt lgkmcnt(0)" ::: "memory");
      __builtin_amdgcn_sched_barrier(0);
      __builtin_amdgcn_s_setprio(1);
#pragma unroll
      for (int i = 0; i < 2; ++i)
#pragma unroll
        for (int j = 0; j < 4; ++j)
#pragma unroll
          for (int ks = 0; ks < 2; ++ks)
            acc[(p << 1) + i][j] = __builtin_amdgcn_mfma_f32_16x16x32_f16(
                af[i][ks], bf[j][ks], acc[(p << 1) + i][j], 0, 0, 0);
      __builtin_amdgcn_s_setprio(0);
      if (p == 3) {     // once per K-tile: A(kt+1),B(kt+1) resident after this
        if (kt + 2 < nk) asm volatile("s_waitcnt vmcnt(4)" ::: "memory");
        else             asm volatile("s_waitcnt vmcnt(0)" ::: "memory");
        __builtin_amdgcn_sched_barrier(0);
      }
      __builtin_amdgcn_s_barrier();                        // trailing
    }
  }

  // epilogue: D frag row = g*4 + r, col = ln15
  if constexpr (STATS) {
    // store P = exp(s) (fp16) and accumulate per-row sum-exp (f32).
    float* Lsh = (float*)sm;   // [256][4] — staging LDS is dead here
    float part[8][4];
#pragma unroll
    for (int i = 0; i < 8; ++i) {
      const int row = bm + (wm << 7) + (i << 4) + (g << 2);
#pragma unroll
      for (int r = 0; r < 4; ++r) {
        float s = 0.f;
#pragma unroll
        for (int j = 0; j < 4; ++j) {
          const int col = bn + (wn << 6) + (j << 4) + ln15;
          float e = fminf(__expf(acc[i][j][r]), 60000.f);
          Ch[(long)(row + r) * N + col] = (_Float16)e;
          s += e;
        }
        // reduce across the 16 lanes sharing g (xor 1,2,4,8 stay in-group)
#pragma unroll
        for (int off = 1; off < 16; off <<= 1) s += __shfl_xor(s, off);
        part[i][r] = s;
      }
    }
    if (ln15 == 0) {
#pragma unroll
      for (int i = 0; i < 8; ++i)
#pragma unroll
        for (int r = 0; r < 4; ++r) {
          const int lrow = (wm << 7) + (i << 4) + (g << 2) + r;
          Lsh[(lrow << 2) + wn] = part[i][r];
        }
    }
    __syncthreads();
    if (tid < 256) {
      float L = Lsh[(tid << 2)] + Lsh[(tid << 2) + 1] +
                Lsh[(tid << 2) + 2] + Lsh[(tid << 2) + 3];
      Lp[(long)(bm + tid) * gridDim.y + byr] = L;
    }
  } else {
#pragma unroll
    for (int i = 0; i < 8; ++i) {
      const int row = bm + (wm << 7) + (i << 4) + (g << 2);
#pragma unroll
      for (int j = 0; j < 4; ++j) {
        const int col = bn + (wn << 6) + (j << 4) + ln15;
#pragma unroll
        for (int r = 0; r < 4; ++r) {
          if constexpr (CMODE == 1)
            Ch[(long)(row + r) * N + col] = (_Float16)acc[i][j][r];
          else
            Cf[(long)(row + r) * N + col] = acc[i][j][r];
        }
      }
    }
  }
}

// ----------------- combine per-block sum-exp -> 1/l per row -----------------
__global__ __launch_bounds__(256) void k_linv(const float* __restrict__ Lp,
                                              float* __restrict__ Linv, int nb) {
  const int r = (blockIdx.x << 8) + threadIdx.x;
  float s = 0.f;
  for (int i = 0; i < nb; ++i) s += Lp[(long)r * nb + i];
  Linv[r] = 1.f / s;
}

// --------------------- split-K reduce: sum 4 f32 slices -> fp16 -------------
__global__ __launch_bounds__(256) void k_red4(const float* __restrict__ p,
                                              _Float16* __restrict__ o,
                                              int n4, float scale) {
  const f32x4* pv = reinterpret_cast<const f32x4*>(p);
  int i = blockIdx.x * blockDim.x + threadIdx.x;
  int st = gridDim.x * blockDim.x;
  for (; i < n4; i += st) {
    f32x4 a = pv[i] + pv[i + n4] + pv[i + 2 * n4] + pv[i + 3 * n4];
    a *= scale;
    reinterpret_cast<f16x4*>(o)[i] = __builtin_convertvector(a, f16x4);
  }
}

// ------ split-K reduce of 8 fp16 slices with per-row 1/l scale (PV->ctx) ----
__global__ __launch_bounds__(256) void k_red8row(const _Float16* __restrict__ p,
                                                 const float* __restrict__ Linv,
                                                 _Float16* __restrict__ o, int n4) {
  const f16x4* pv = reinterpret_cast<const f16x4*>(p);
  int i = blockIdx.x * blockDim.x + threadIdx.x;
  int st = gridDim.x * blockDim.x;
  for (; i < n4; i += st) {
    f32x4 a = __builtin_convertvector(pv[i], f32x4);
#pragma unroll
    for (int s = 1; s < 8; ++s)
      a += __builtin_convertvector(pv[i + (long)s * n4], f32x4);
    a *= Linv[i >> 7];                      // 128 f16x4 groups per 512-col row
    reinterpret_cast<f16x4*>(o)[i] = __builtin_convertvector(a, f16x4);
  }
}

// ------------------------------- launcher ----------------------------------

extern "C" void kernel_launch(void* const* d_in, const int* in_sizes, int n_in,
                              void* d_out, int out_size, void* d_ws, size_t ws_size,
                              hipStream_t stream) {
  const float* x     = (const float*)d_in[0];
  const float* cache = (const float*)d_in[1];
  const float* W_kv  = (const float*)d_in[2];
  const float* W_q   = (const float*)d_in[3];
  const float* W_lq  = (const float*)d_in[4];
  const float* W_o   = (const float*)d_in[5];

  float* out     = (float*)d_out;                 // (8192, 2048) f32
  float* lkv_out = out + (size_t)8192 * 2048;     // (2, 8192, 512) f32

  // scratch overlay in d_out's "out" region (dead before final GEMM writes it)
  _Float16* base16 = (_Float16*)d_out;
  _Float16* x16    = base16;                      // [0, 16.78M) live->fused GEMM
  _Float16* lq16   = base16 + 16777216;           // live -> S-GEMM
  _Float16* WlqT   = base16 + 25165824;           // dead after Wcomb GEMM
  _Float16* WcombT = base16 + 26214400;           // dead after fused GEMM
  _Float16* WkvT   = base16 + 27262976;           // adjacent to WcombT (B concat)
  _Float16* lkvT16 = base16 + 20971520;           // spans ..29,360,128
  _Float16* PVp16  = base16;                      // PV fp16 partials overlay x16
                                                  // (8 * CR * 512 * 2B <= 33.5MB)
  float*    Lp     = (float*)(base16 + 29360128); // CR*32 f32 (<=512KB)
  float*    Linv   = Lp + 131072;                 // CR f32

  // ws: lkv16 16.8MB | ctx 8.4MB | WoT 2MB | S chunk
  _Float16* lkv16 = (_Float16*)d_ws;              // 8,388,608 elems
  _Float16* ctx   = lkv16 + 8388608;              // 4,194,304
  _Float16* WoT   = ctx + 4194304;                // 1,048,576
  _Float16* Sbuf  = WoT + 1048576;                // CR*8192 elems
  float*    Wcp   = (float*)Sbuf;                 // Wcomb split-K f32 partials

  // S chunk rows: pick largest fitting ws_size (base usage = 27,262,976 B)
  const size_t sbase = 27262976;
  int CR = 1024;
  if (ws_size >= sbase + (size_t)4096 * 8192 * 2) CR = 4096;
  else if (ws_size >= sbase + (size_t)2048 * 8192 * 2) CR = 2048;

  const float iscale = 0.044194173824159216f;  // 1/sqrt(512)

  hipFuncSetAttribute((const void*)k_gemm256<1, 1, 0>,
                      hipFuncAttributeMaxDynamicSharedMemorySize, 131072);
  hipFuncSetAttribute((const void*)k_gemm256<0, 0, 0>,
                      hipFuncAttributeMaxDynamicSharedMemorySize, 131072);
  hipFuncSetAttribute((const void*)k_gemm256<1, 0, 1>,
                      hipFuncAttributeMaxDynamicSharedMemorySize, 131072);

  // converts / transposes (W_q consumed f32-direct; x pre-converted: the
  // fused GEMM re-reads A 8x, so one-pass fp16 conversion wins)
  k_cvt<<<1024, 256, 0, stream>>>(x, x16, 16777216 / 4);
  k_cache<<<1024, 256, 0, stream>>>(cache, lkv_out, lkv16, 4194304 / 4);
  k_tc<<<dim3(16, 64), 256, 0, stream>>>(W_kv, WkvT, 2048, 512);
  k_tc<<<dim3(16, 64), 256, 0, stream>>>(W_lq, WlqT, 2048, 512);
  k_tc<<<dim3(64, 16), 256, 0, stream>>>(W_o, WoT, 512, 2048);

  // W_comb^T[l][d] = sum_e WlqT[l][e]*W_q[d][e] : split-K x4 (B read f32)
  k_gemm<4, 0, 1, 0><<<dim3(4, 16, 4), 256, 0, stream>>>(
      WlqT, W_q, Wcp, nullptr, nullptr, 512, 2048, 512, 2048, 2048, 1.f);
  k_red4<<<1024, 256, 0, stream>>>(Wcp, WcombT, (512 * 2048) / 4, iscale);
  // fused: [lq | l_kv_new] = x16 @ [WcombT ; WkvT]^T  (N=1024, XCD swizzle)
  k_gemm<5, 0, 0, 1><<<dim3(64, 8), 256, 0, stream>>>(
      x16, WcombT, lkv_out, lq16, lkv16, 8192, 1024, 2048, 2048, 2048, 1.f);
  // l_kv^T (512 x 16384) into d_out spare
  k_tb<<<dim3(16, 512), 256, 0, stream>>>(lkv16, lkvT16, 16384, 512);

  // attention per CR-row chunk: P=exp(S) (+sum-exp), 1/l, PV, scaled reduce
  for (long r0 = 0; r0 < 8192; r0 += CR) {
    const long b = r0 >> 12;
    // P = exp(lq_chunk @ l_kv_b^T)  (fp16) + per-(row, col-block) sum-exp
    k_gemm256<1, 1, 0><<<dim3(CR >> 8, 32), 512, 131072, stream>>>(
        lq16 + r0 * 512, lkv16 + b * 8192 * 512, nullptr, Sbuf, Lp,
        CR, 8192, 512, 512, 512);
    k_linv<<<CR >> 8, 256, 0, stream>>>(Lp, Linv, 32);
    // ctx_chunk = P @ V : 256-tile split-K x8 (Ks=1024) -> fp16 partials
    k_gemm256<1, 0, 1><<<dim3(CR >> 8, 2, 8), 512, 131072, stream>>>(
        Sbuf, lkvT16 + b * 8192, nullptr, PVp16, nullptr,
        CR, 512, 1024, 8192, 16384);
    // reduce 8 slices + per-row 1/l
    k_red8row<<<2048, 256, 0, stream>>>(PVp16, Linv, ctx + r0 * 512, (CR * 512) / 4);
  }

  // out = ctx @ W_o — 256-tile 4-phase core
  k_gemm256<0, 0, 0><<<dim3(32, 8), 512, 131072, stream>>>(ctx, WoT, out, nullptr,
                                                           nullptr,
                                                           8192, 2048, 512, 512, 512);
}

// Round 15
// 318.960 us; speedup vs baseline: 1.0635x; 1.0427x over previous
//
#include <hip/hip_runtime.h>
#include <hip/hip_bf16.h>
#include <math.h>

// ---------------------------------------------------------------------------
// MHLA: out, l_kv = MLA(x, cache, W_kv, W_q, W_lq, W_o)
//   l_kv_new = x @ W_kv ; lq = x @ (W_q @ W_lq) * 1/sqrt(512)  [folded+scaled]
//   l_kv = concat(cache, l_kv_new)
//   P = exp(lq @ l_kv^T)  (fp16, chunked; exp + row sum-exp in S-GEMM epilogue)
//   ctx = (P @ l_kv) * (1/l)   [256-tile split-K x8 -> fp16 partials -> reduce]
//   out = ctx @ W_o
// k_gemm256: 4-phase/K-tile counted-vmcnt pipeline (validated round 14).
// This round: launch consolidation only — k_prep merges the 5 preprocessing
// kernels; k_red8row computes 1/l inline (k_linv removed). 12 launches total.
// ---------------------------------------------------------------------------

typedef _Float16 f16x8 __attribute__((ext_vector_type(8)));
typedef _Float16 f16x4 __attribute__((ext_vector_type(4)));
typedef float    f32x4 __attribute__((ext_vector_type(4)));
typedef float    f32x8 __attribute__((ext_vector_type(8)));

// async 16B global->LDS (per-lane global addr; LDS dest = uniform base + lane*16)
__device__ __forceinline__ void gl_lds16(const void* g, void* l) {
  __builtin_amdgcn_global_load_lds(
      (const __attribute__((address_space(1))) void*)g,
      (__attribute__((address_space(3))) void*)l, 16, 0, 0);
}

// ------------------- merged preprocessing (1 launch, 5120 blocks) ----------
// b in [0,1024):    x f32 -> x16 fp16              (grid-stride, 1024 blocks)
// b in [1024,2048): cache -> l_kv f32 rows + fp16  (grid-stride, 1024 blocks)
// b in [2048,3072): W_kv  (2048x512)  -> WkvT  (512x2048)  transpose+convert
// b in [3072,4096): W_lq  (2048x512)  -> WlqT  (512x2048)
// b in [4096,5120): W_o   (512x2048)  -> WoT   (2048x512)
__global__ __launch_bounds__(256) void k_prep(const float* __restrict__ x,
                                              _Float16* __restrict__ x16,
                                              const float* __restrict__ cache,
                                              float* __restrict__ lkv_f32,
                                              _Float16* __restrict__ lkv16,
                                              const float* __restrict__ Wkv,
                                              _Float16* __restrict__ WkvT,
                                              const float* __restrict__ Wlq,
                                              _Float16* __restrict__ WlqT,
                                              const float* __restrict__ Wo,
                                              _Float16* __restrict__ WoT) {
  __shared__ float t[32][33];
  const int b = blockIdx.x;
  const int tid = threadIdx.x;
  if (b < 1024) {
    const int st = 1024 * 256;
    for (int i = b * 256 + tid; i < 4194304; i += st) {
      f32x4 v = reinterpret_cast<const f32x4*>(x)[i];
      reinterpret_cast<f16x4*>(x16)[i] = __builtin_convertvector(v, f16x4);
    }
  } else if (b < 2048) {
    const int st = 1024 * 256;
    for (int i = (b - 1024) * 256 + tid; i < 1048576; i += st) {
      f32x4 v = reinterpret_cast<const f32x4*>(cache)[i];
      int e = i << 2;
      int bb = e >> 21;                // 4096*512 = 2^21
      int dst = e + (bb << 21);        // batch stride in l_kv is 2^22
      *reinterpret_cast<f32x4*>(lkv_f32 + dst) = v;
      *reinterpret_cast<f16x4*>(lkv16 + dst) = __builtin_convertvector(v, f16x4);
    }
  } else {
    const float* in; _Float16* outp; int R, C, bx, by;
    if (b < 3072) {
      in = Wkv; outp = WkvT; R = 2048; C = 512;
      const int bb = b - 2048; bx = bb & 15; by = bb >> 4;
    } else if (b < 4096) {
      in = Wlq; outp = WlqT; R = 2048; C = 512;
      const int bb = b - 3072; bx = bb & 15; by = bb >> 4;
    } else {
      in = Wo; outp = WoT; R = 512; C = 2048;
      const int bb = b - 4096; bx = bb & 63; by = bb >> 6;
    }
    const int c0 = bx << 5, r0 = by << 5;
    {
      int r = tid >> 3, c4 = (tid & 7) << 2;
      f32x4 v = *reinterpret_cast<const f32x4*>(&in[(long)(r0 + r) * C + c0 + c4]);
      t[r][c4] = v[0]; t[r][c4 + 1] = v[1]; t[r][c4 + 2] = v[2]; t[r][c4 + 3] = v[3];
    }
    __syncthreads();
    {
      int c = tid >> 3, r4 = (tid & 7) << 2;
      f16x4 o = {(_Float16)t[r4][c], (_Float16)t[r4 + 1][c],
                 (_Float16)t[r4 + 2][c], (_Float16)t[r4 + 3][c]};
      *reinterpret_cast<f16x4*>(&outp[(long)(c0 + c) * R + r0 + r4]) = o;
    }
  }
}

// transpose fp16: in (R x C) -> out (C x R)
__global__ __launch_bounds__(256) void k_tb(const _Float16* __restrict__ in,
                                            _Float16* __restrict__ out, int R, int C) {
  __shared__ _Float16 t[32][36];
  const int c0 = blockIdx.x << 5, r0 = blockIdx.y << 5;
  const int tid = threadIdx.x;
  {
    int r = tid >> 3, c4 = (tid & 7) << 2;
    f16x4 v = *reinterpret_cast<const f16x4*>(&in[(long)(r0 + r) * C + c0 + c4]);
    t[r][c4] = v[0]; t[r][c4 + 1] = v[1]; t[r][c4 + 2] = v[2]; t[r][c4 + 3] = v[3];
  }
  __syncthreads();
  {
    int c = tid >> 3, r4 = (tid & 7) << 2;
    f16x4 o = {t[r4][c], t[r4 + 1][c], t[r4 + 2][c], t[r4 + 3][c]};
    *reinterpret_cast<f16x4*>(&out[(long)(c0 + c) * R + r0 + r4]) = o;
  }
}

// ------------------------- GEMM (128x128, reg-staged) ----------------------
// C[M,N] = A[M,K] @ B^T where A is [M][lda], B is [N][ldb] (K-contig rows).
// AF32/BF32: f32 operand converted during staging. SWZ: XCD-chunked remap.
// CMODE: 0 f32 C ; 1 fp16 C ; 3 fp16 scaled ; 4 split-K f32 partial ;
// 5 fused lq|lkv epilogue.
template <int CMODE, int AF32, int BF32, int SWZ>
__global__ __launch_bounds__(256) void k_gemm(const void* __restrict__ Av,
                                              const void* __restrict__ Bv,
                                              float* __restrict__ Cf,
                                              _Float16* __restrict__ Ch,
                                              _Float16* __restrict__ Ch2,
                                              int M, int N, int K, int lda, int ldb,
                                              float cscale) {
  const _Float16* A16 = (const _Float16*)Av;
  const float*    A32 = (const float*)Av;
  const _Float16* B16 = (const _Float16*)Bv;
  const float*    B32 = (const float*)Bv;
  if constexpr (CMODE == 4) {
    const long z = blockIdx.z;
    A16 += z * K; A32 += z * K;
    B16 += z * K; B32 += z * K;
    Cf += z * (long)M * N;
  }
  int bxr = blockIdx.x, byr = blockIdx.y;
  if constexpr (SWZ) {
    const int nbx = gridDim.x, nby = gridDim.y, nwg = nbx * nby;
    if ((nwg & 7) == 0) {
      const int orig = bxr * nby + byr;
      const int q = nwg >> 3;
      const int wg = (orig & 7) * q + (orig >> 3);
      bxr = wg / nby; byr = wg % nby;
    }
  }
  __shared__ alignas(16) _Float16 As[128 * 64];
  __shared__ alignas(16) _Float16 Bs[128 * 64];
  const int tid = threadIdx.x;
  const int lane = tid & 63;
  const int w = tid >> 6;
  const int wr = ((w >> 1) & 1) << 6, wc = (w & 1) << 6;
  const int bm = bxr << 7, bn = byr << 7;
  const int g = lane >> 4, ln15 = lane & 15;

  f32x4 acc[4][4] = {};

  const int srowl = lane >> 3;
  const int skcol = (lane & 7) << 3;
  const int wofs = (srowl << 6) + (((lane & 7) ^ srowl) << 3);

  f16x8 ra[4], rb[4];
  auto loadregs = [&](int k0) {
#pragma unroll
    for (int i = 0; i < 4; ++i) {
      int ch = (w << 2) + i;
      int row = (ch << 3) + srowl;
      if constexpr (AF32) {
        f32x8 v = *reinterpret_cast<const f32x8*>(&A32[(long)(bm + row) * lda + k0 + skcol]);
        ra[i] = __builtin_convertvector(v, f16x8);
      } else {
        ra[i] = *reinterpret_cast<const f16x8*>(&A16[(long)(bm + row) * lda + k0 + skcol]);
      }
      if constexpr (BF32) {
        f32x8 v = *reinterpret_cast<const f32x8*>(&B32[(long)(bn + row) * ldb + k0 + skcol]);
        rb[i] = __builtin_convertvector(v, f16x8);
      } else {
        rb[i] = *reinterpret_cast<const f16x8*>(&B16[(long)(bn + row) * ldb + k0 + skcol]);
      }
    }
  };
  loadregs(0);
  const int nk = K >> 6;
  for (int kt = 0; kt < nk; ++kt) {
    __syncthreads();
#pragma unroll
    for (int i = 0; i < 4; ++i) {
      int ch = (w << 2) + i;
      *reinterpret_cast<f16x8*>(&As[(ch << 9) + wofs]) = ra[i];
      *reinterpret_cast<f16x8*>(&Bs[(ch << 9) + wofs]) = rb[i];
    }
    __syncthreads();
    if (kt + 1 < nk) loadregs((kt + 1) << 6);
#pragma unroll
    for (int ks = 0; ks < 2; ++ks) {
      f16x8 af[4], bf[4];
#pragma unroll
      for (int i = 0; i < 4; ++i) {
        const int arow = wr + (i << 4) + ln15;
        const int brow = wc + (i << 4) + ln15;
        const int inner = (((ks << 5) + (g << 3)) ^ ((ln15 & 7) << 3));
        af[i] = *reinterpret_cast<const f16x8*>(&As[arow * 64 + inner]);
        bf[i] = *reinterpret_cast<const f16x8*>(&Bs[brow * 64 + inner]);
      }
#pragma unroll
      for (int i = 0; i < 4; ++i)
#pragma unroll
        for (int j = 0; j < 4; ++j)
          acc[i][j] = __builtin_amdgcn_mfma_f32_16x16x32_f16(af[i], bf[j], acc[i][j], 0, 0, 0);
    }
  }
#pragma unroll
  for (int i = 0; i < 4; ++i) {
    const int row = bm + wr + (i << 4) + (g << 2);
#pragma unroll
    for (int j = 0; j < 4; ++j) {
      const int col = bn + wc + (j << 4) + ln15;
#pragma unroll
      for (int r = 0; r < 4; ++r) {
        float v = acc[i][j][r];
        long orow = row + r;
        if constexpr (CMODE == 1) {
          Ch[orow * N + col] = (_Float16)v;
        } else if constexpr (CMODE == 3) {
          Ch[orow * N + col] = (_Float16)(v * cscale);
        } else if constexpr (CMODE == 5) {
          if (col < 512) {
            Ch[orow * 512 + col] = (_Float16)v;               // lq16
          } else {
            long m2 = ((orow >> 12) << 13) + 4096 + (orow & 4095);
            Cf[m2 * 512 + (col - 512)] = v;                   // l_kv f32
            Ch2[m2 * 512 + (col - 512)] = (_Float16)v;        // l_kv fp16
          }
        } else {  // 0, 4
          Cf[orow * N + col] = v;
        }
      }
    }
  }
}

// ------- GEMM (256x256, 8 waves, 4-phase/K-tile counted-vmcnt pipeline) ----
// LDS per operand: 4 half-slots (2 bufs x 2 row-halves), 16KB each.
// Wave (wm,wn) consumes A-half wm (slot buf*2+wm) and B-half wn>>1.
// bf register-cached per K-tile (read @P0); af reloaded per phase.
// CMODE: 0 = f32 C, 1 = fp16 C. STATS=1: store exp(acc) + row sum-exp.
// SPLITK=1: blockIdx.z = K-slice; fp16 partials in Ch.
template <int CMODE, int STATS, int SPLITK>
__global__ __launch_bounds__(512, 2) void k_gemm256(const _Float16* __restrict__ A,
                                                    const _Float16* __restrict__ B,
                                                    float* __restrict__ Cf,
                                                    _Float16* __restrict__ Ch,
                                                    float* __restrict__ Lp,
                                                    int M, int N, int K,
                                                    int lda, int ldb) {
  extern __shared__ _Float16 sm[];
  _Float16* As = sm;             // 4 slots x 8192 elems (buf*2+half)
  _Float16* Bs = sm + 32768;
  if constexpr (SPLITK) {
    const long z = blockIdx.z;
    A += z * (long)K;
    B += z * (long)K;
    Ch += z * (long)M * N;
  }
  int bxr = blockIdx.x, byr = blockIdx.y;
  {
    const int nbx = gridDim.x, nby = gridDim.y, nwg = nbx * nby;
    if ((nwg & 7) == 0) {
      const int orig = bxr * nby + byr;      // M-major linearization
      const int q = nwg >> 3;
      const int wg = (orig & 7) * q + (orig >> 3);  // XCD-chunked (bijective)
      bxr = wg / nby; byr = wg % nby;
    }
  }
  const int tid = threadIdx.x;
  const int lane = tid & 63;
  const int w = tid >> 6;             // 0..7
  const int wm = w >> 2, wn = w & 3;  // 2 x 4 wave grid; wave out = 128x64
  const int bm = bxr << 8, bn = byr << 8;
  const int g = lane >> 4, ln15 = lane & 15;

  f32x4 acc[8][4] = {};

  const int lrow8 = lane >> 3;
  const int lswz  = ((lane & 7) ^ lrow8) << 3;   // pre-swizzled col (elems)
  const int nk = K >> 6;

  // stage one half-tile (128 rows x 64 cols) of operand for K-tile kt: 2 loads
  auto stageA = [&](int half, int kt) {
    const int slot = ((kt & 1) << 1) + half;
    const long k0 = (long)kt << 6;
#pragma unroll
    for (int l = 0; l < 2; ++l) {
      const int row = (half << 7) + (l << 6) + (w << 3) + lrow8;
      gl_lds16(&A[(long)(bm + row) * lda + k0 + lswz],
               &As[slot * 8192 + (((l << 6) + (w << 3)) << 6)]);
    }
  };
  auto stageB = [&](int half, int kt) {
    const int slot = ((kt & 1) << 1) + half;
    const long k0 = (long)kt << 6;
#pragma unroll
    for (int l = 0; l < 2; ++l) {
      const int row = (half << 7) + (l << 6) + (w << 3) + lrow8;
      gl_lds16(&B[(long)(bn + row) * ldb + k0 + lswz],
               &Bs[slot * 8192 + (((l << 6) + (w << 3)) << 6)]);
    }
  };

  // prologue: B(0), A(0), B(1); wait leaves only B(1) (4 loads) in flight
  stageB(0, 0); stageB(1, 0);
  stageA(0, 0); stageA(1, 0);
  if (nk > 1) { stageB(0, 1); stageB(1, 1); }
  if (nk > 1) asm volatile("s_waitcnt vmcnt(4)" ::: "memory");
  else        asm volatile("s_waitcnt vmcnt(0)" ::: "memory");
  __builtin_amdgcn_sched_barrier(0);
  __builtin_amdgcn_s_barrier();

  f16x8 bf[4][2];
  for (int kt = 0; kt < nk; ++kt) {
    const int aslot = ((kt & 1) << 1) + wm;
    const int bslot = ((kt & 1) << 1) + (wn >> 1);
    const int brow0 = (wn & 1) << 6;
#pragma unroll
    for (int p = 0; p < 4; ++p) {
      // --- ds_read register subtile
      if (p == 0) {
#pragma unroll
        for (int j = 0; j < 4; ++j)
#pragma unroll
          for (int ks = 0; ks < 2; ++ks) {
            const int inner = ((ks << 5) + (g << 3)) ^ ((ln15 & 7) << 3);
            bf[j][ks] = *reinterpret_cast<const f16x8*>(
                &Bs[bslot * 8192 + (brow0 + (j << 4) + ln15) * 64 + inner]);
          }
      }
      f16x8 af[2][2];
#pragma unroll
      for (int i = 0; i < 2; ++i)
#pragma unroll
        for (int ks = 0; ks < 2; ++ks) {
          const int mf = (p << 1) + i;
          const int inner = ((ks << 5) + (g << 3)) ^ ((ln15 & 7) << 3);
          af[i][ks] = *reinterpret_cast<const f16x8*>(
              &As[aslot * 8192 + ((mf << 4) + ln15) * 64 + inner]);
        }
      // --- stage 1 half-tile (pacing: A(kt+1) @P0,P1 ; B(kt+2) @P2,P3)
      if (p == 0 && kt + 1 < nk) stageA(0, kt + 1);
      if (p == 1 && kt + 1 < nk) stageA(1, kt + 1);
      if (p == 2 && kt + 2 < nk) stageB(0, kt + 2);
      if (p == 3 && kt + 2 < nk) stageB(1, kt + 2);
      __builtin_amdgcn_s_barrier();                        // mid
      asm volatile("s_waitcnt lgkmcnt(0)" ::: "memory");
      __builtin_amdgcn_sched_barrier(0);
      __builtin_amdgcn_s_setprio(1);
#pragma unroll
      for (int i = 0; i < 2; ++i)
#pragma unroll
        for (int j = 0; j < 4; ++j)
#pragma unroll
          for (int ks = 0; ks < 2; ++ks)
            acc[(p << 1) + i][j] = __builtin_amdgcn_mfma_f32_16x16x32_f16(
                af[i][ks], bf[j][ks], acc[(p << 1) + i][j], 0, 0, 0);
      __builtin_amdgcn_s_setprio(0);
      if (p == 3) {     // once per K-tile: A(kt+1),B(kt+1) resident after this
        if (kt + 2 < nk) asm volatile("s_waitcnt vmcnt(4)" ::: "memory");
        else             asm volatile("s_waitcnt vmcnt(0)" ::: "memory");
        __builtin_amdgcn_sched_barrier(0);
      }
      __builtin_amdgcn_s_barrier();                        // trailing
    }
  }

  // epilogue: D frag row = g*4 + r, col = ln15
  if constexpr (STATS) {
    // store P = exp(s) (fp16) and accumulate per-row sum-exp (f32).
    float* Lsh = (float*)sm;   // [256][4] — staging LDS is dead here
    float part[8][4];
#pragma unroll
    for (int i = 0; i < 8; ++i) {
      const int row = bm + (wm << 7) + (i << 4) + (g << 2);
#pragma unroll
      for (int r = 0; r < 4; ++r) {
        float s = 0.f;
#pragma unroll
        for (int j = 0; j < 4; ++j) {
          const int col = bn + (wn << 6) + (j << 4) + ln15;
          float e = fminf(__expf(acc[i][j][r]), 60000.f);
          Ch[(long)(row + r) * N + col] = (_Float16)e;
          s += e;
        }
        // reduce across the 16 lanes sharing g (xor 1,2,4,8 stay in-group)
#pragma unroll
        for (int off = 1; off < 16; off <<= 1) s += __shfl_xor(s, off);
        part[i][r] = s;
      }
    }
    if (ln15 == 0) {
#pragma unroll
      for (int i = 0; i < 8; ++i)
#pragma unroll
        for (int r = 0; r < 4; ++r) {
          const int lrow = (wm << 7) + (i << 4) + (g << 2) + r;
          Lsh[(lrow << 2) + wn] = part[i][r];
        }
    }
    __syncthreads();
    if (tid < 256) {
      float L = Lsh[(tid << 2)] + Lsh[(tid << 2) + 1] +
                Lsh[(tid << 2) + 2] + Lsh[(tid << 2) + 3];
      Lp[(long)(bm + tid) * gridDim.y + byr] = L;
    }
  } else {
#pragma unroll
    for (int i = 0; i < 8; ++i) {
      const int row = bm + (wm << 7) + (i << 4) + (g << 2);
#pragma unroll
      for (int j = 0; j < 4; ++j) {
        const int col = bn + (wn << 6) + (j << 4) + ln15;
#pragma unroll
        for (int r = 0; r < 4; ++r) {
          if constexpr (CMODE == 1)
            Ch[(long)(row + r) * N + col] = (_Float16)acc[i][j][r];
          else
            Cf[(long)(row + r) * N + col] = acc[i][j][r];
        }
      }
    }
  }
}

// --------------------- split-K reduce: sum 4 f32 slices -> fp16 -------------
__global__ __launch_bounds__(256) void k_red4(const float* __restrict__ p,
                                              _Float16* __restrict__ o,
                                              int n4, float scale) {
  const f32x4* pv = reinterpret_cast<const f32x4*>(p);
  int i = blockIdx.x * blockDim.x + threadIdx.x;
  int st = gridDim.x * blockDim.x;
  for (; i < n4; i += st) {
    f32x4 a = pv[i] + pv[i + n4] + pv[i + 2 * n4] + pv[i + 3 * n4];
    a *= scale;
    reinterpret_cast<f16x4*>(o)[i] = __builtin_convertvector(a, f16x4);
  }
}

// --- split-K reduce of 8 fp16 slices, 1/l computed inline from Lp (PV->ctx) -
__global__ __launch_bounds__(256) void k_red8row(const _Float16* __restrict__ p,
                                                 const float* __restrict__ Lp,
                                                 _Float16* __restrict__ o, int n4) {
  const f16x4* pv = reinterpret_cast<const f16x4*>(p);
  int i = blockIdx.x * blockDim.x + threadIdx.x;
  int st = gridDim.x * blockDim.x;
  for (; i < n4; i += st) {
    f32x4 a = __builtin_convertvector(pv[i], f32x4);
#pragma unroll
    for (int s = 1; s < 8; ++s)
      a += __builtin_convertvector(pv[i + (long)s * n4], f32x4);
    const long row = i >> 7;                // 128 f16x4 groups per 512-col row
    float l = 0.f;
#pragma unroll
    for (int j = 0; j < 32; ++j) l += Lp[row * 32 + j];   // L2-broadcast reads
    a *= (1.f / l);
    reinterpret_cast<f16x4*>(o)[i] = __builtin_convertvector(a, f16x4);
  }
}

// ------------------------------- launcher ----------------------------------

extern "C" void kernel_launch(void* const* d_in, const int* in_sizes, int n_in,
                              void* d_out, int out_size, void* d_ws, size_t ws_size,
                              hipStream_t stream) {
  const float* x     = (const float*)d_in[0];
  const float* cache = (const float*)d_in[1];
  const float* W_kv  = (const float*)d_in[2];
  const float* W_q   = (const float*)d_in[3];
  const float* W_lq  = (const float*)d_in[4];
  const float* W_o   = (const float*)d_in[5];

  float* out     = (float*)d_out;                 // (8192, 2048) f32
  float* lkv_out = out + (size_t)8192 * 2048;     // (2, 8192, 512) f32

  // scratch overlay in d_out's "out" region (dead before final GEMM writes it)
  _Float16* base16 = (_Float16*)d_out;
  _Float16* x16    = base16;                      // [0, 16.78M) live->fused GEMM
  _Float16* lq16   = base16 + 16777216;           // live -> S-GEMM
  _Float16* WlqT   = base16 + 25165824;           // dead after Wcomb GEMM
  _Float16* WcombT = base16 + 26214400;           // dead after fused GEMM
  _Float16* WkvT   = base16 + 27262976;           // adjacent to WcombT (B concat)
  _Float16* lkvT16 = base16 + 20971520;           // spans ..29,360,128
  _Float16* PVp16  = base16;                      // PV fp16 partials overlay x16
                                                  // (8 * CR * 512 * 2B <= 33.5MB)
  float*    Lp     = (float*)(base16 + 29360128); // CR*32 f32 (<=512KB)

  // ws: lkv16 16.8MB | ctx 8.4MB | WoT 2MB | S chunk
  _Float16* lkv16 = (_Float16*)d_ws;              // 8,388,608 elems
  _Float16* ctx   = lkv16 + 8388608;              // 4,194,304
  _Float16* WoT   = ctx + 4194304;                // 1,048,576
  _Float16* Sbuf  = WoT + 1048576;                // CR*8192 elems
  float*    Wcp   = (float*)Sbuf;                 // Wcomb split-K f32 partials

  // S chunk rows: pick largest fitting ws_size (base usage = 27,262,976 B)
  const size_t sbase = 27262976;
  int CR = 1024;
  if (ws_size >= sbase + (size_t)4096 * 8192 * 2) CR = 4096;
  else if (ws_size >= sbase + (size_t)2048 * 8192 * 2) CR = 2048;

  const float iscale = 0.044194173824159216f;  // 1/sqrt(512)

  hipFuncSetAttribute((const void*)k_gemm256<1, 1, 0>,
                      hipFuncAttributeMaxDynamicSharedMemorySize, 131072);
  hipFuncSetAttribute((const void*)k_gemm256<0, 0, 0>,
                      hipFuncAttributeMaxDynamicSharedMemorySize, 131072);
  hipFuncSetAttribute((const void*)k_gemm256<1, 0, 1>,
                      hipFuncAttributeMaxDynamicSharedMemorySize, 131072);

  // merged preprocessing: x cvt, cache copy, W_kv/W_lq/W_o transposes
  k_prep<<<5120, 256, 0, stream>>>(x, x16, cache, lkv_out, lkv16,
                                   W_kv, WkvT, W_lq, WlqT, W_o, WoT);

  // W_comb^T[l][d] = sum_e WlqT[l][e]*W_q[d][e] : split-K x4 (B read f32)
  k_gemm<4, 0, 1, 0><<<dim3(4, 16, 4), 256, 0, stream>>>(
      WlqT, W_q, Wcp, nullptr, nullptr, 512, 2048, 512, 2048, 2048, 1.f);
  k_red4<<<1024, 256, 0, stream>>>(Wcp, WcombT, (512 * 2048) / 4, iscale);
  // fused: [lq | l_kv_new] = x16 @ [WcombT ; WkvT]^T  (N=1024, XCD swizzle)
  k_gemm<5, 0, 0, 1><<<dim3(64, 8), 256, 0, stream>>>(
      x16, WcombT, lkv_out, lq16, lkv16, 8192, 1024, 2048, 2048, 2048, 1.f);
  // l_kv^T (512 x 16384) into d_out spare
  k_tb<<<dim3(16, 512), 256, 0, stream>>>(lkv16, lkvT16, 16384, 512);

  // attention per CR-row chunk: P=exp(S) (+sum-exp), PV, scaled reduce
  for (long r0 = 0; r0 < 8192; r0 += CR) {
    const long b = r0 >> 12;
    // P = exp(lq_chunk @ l_kv_b^T)  (fp16) + per-(row, col-block) sum-exp
    k_gemm256<1, 1, 0><<<dim3(CR >> 8, 32), 512, 131072, stream>>>(
        lq16 + r0 * 512, lkv16 + b * 8192 * 512, nullptr, Sbuf, Lp,
        CR, 8192, 512, 512, 512);
    // ctx_chunk = P @ V : 256-tile split-K x8 (Ks=1024) -> fp16 partials
    k_gemm256<1, 0, 1><<<dim3(CR >> 8, 2, 8), 512, 131072, stream>>>(
        Sbuf, lkvT16 + b * 8192, nullptr, PVp16, nullptr,
        CR, 512, 1024, 8192, 16384);
    // reduce 8 slices + per-row 1/l (computed inline from Lp)
    k_red8row<<<2048, 256, 0, stream>>>(PVp16, Lp, ctx + r0 * 512, (CR * 512) / 4);
  }

  // out = ctx @ W_o — 256-tile 4-phase core
  k_gemm256<0, 0, 0><<<dim3(32, 8), 512, 131072, stream>>>(ctx, WoT, out, nullptr,
                                                           nullptr,
                                                           8192, 2048, 512, 512, 512);
}